// Round 5
// baseline (322.891 us; speedup 1.0000x reference)
//
#include <hip/hip_runtime.h>
#include <stdint.h>

typedef short v8s __attribute__((ext_vector_type(8)));
typedef short v4s __attribute__((ext_vector_type(4)));
typedef float v4f __attribute__((ext_vector_type(4)));

#define BM 256         // rows per block (4 waves, wave grid 2x2, 128x64/wave)
#define BN 128
#define BKH 32         // shorts per row per k-step (64 B)
#define ASH (BM * BKH)          // A region shorts per buffer (16 KB)
#define TSH ((BM + BN) * BKH)   // shorts per buffer = 12288 (24 KB)
#define POS_INF __builtin_inff()

typedef __attribute__((address_space(3))) unsigned int lds_uint;
typedef const __attribute__((address_space(1))) unsigned int glb_uint;

__device__ __forceinline__ void load16_lds(const void* g, void* l) {
    // 16B per lane, LDS dest = wave-uniform base + lane*16
    __builtin_amdgcn_global_load_lds((glb_uint*)g, (lds_uint*)l, 16, 0, 0);
}

__device__ __forceinline__ short f2bf(float f) {
    uint32_t u = __builtin_bit_cast(uint32_t, f);
    u += 0x7fffu + ((u >> 16) & 1u);
    return (short)(u >> 16);
}

// Fused prep (unchanged from the verified 283us kernel).
__global__ void prep(const float* __restrict__ centers,
                     unsigned short* __restrict__ cbf,
                     int C, int D, int CP, int CB,
                     const float* __restrict__ x,
                     unsigned short* __restrict__ xbf, size_t nx,
                     int* __restrict__ cnt, int NB,
                     float* __restrict__ out) {
    const int b = blockIdx.x;
    const int t = threadIdx.x;
    if (b == 0 && t == 0) out[0] = 0.0f;
    if (b < CB) {
        const int g = b * 256 + t;
        if (g < NB) cnt[g] = 0;
        const int wave = t >> 6, lane = t & 63;
        const int row = b * 4 + wave;
        if (row >= CP) return;
        if (row >= C) {
            v4s z = {0, 0, 0, 0};
            for (int d = lane * 4; d < D; d += 256)
                *(v4s*)&cbf[(size_t)row * D + d] = z;
            return;
        }
        const float* src = centers + (size_t)row * D;
        float ss = 0.0f;
        for (int d = lane * 4; d < D; d += 256) {
            v4f f = *(const v4f*)&src[d];
            ss += f.x * f.x + f.y * f.y + f.z * f.z + f.w * f.w;
        }
        #pragma unroll
        for (int off = 32; off; off >>= 1) ss += __shfl_xor(ss, off, 64);
        const float rn = rsqrtf(ss);
        for (int d = lane * 4; d < D; d += 256) {
            v4f f = *(const v4f*)&src[d];
            v4s s;
            s.x = f2bf(f.x * rn); s.y = f2bf(f.y * rn);
            s.z = f2bf(f.z * rn); s.w = f2bf(f.w * rn);
            *(v4s*)&cbf[(size_t)row * D + d] = s;
        }
    } else {
        const size_t i = ((size_t)(b - CB) * 256 + t) * 8;
        if (i >= nx) return;
        v4f f0 = *(const v4f*)&x[i];
        v4f f1 = *(const v4f*)&x[i + 4];
        v8s s;
        s[0] = f2bf(f0.x); s[1] = f2bf(f0.y); s[2] = f2bf(f0.z); s[3] = f2bf(f0.w);
        s[4] = f2bf(f1.x); s[5] = f2bf(f1.y); s[6] = f2bf(f1.z); s[7] = f2bf(f1.w);
        *(v8s*)&xbf[i] = s;
    }
}

// Fused GEMM + row-min epilogue + last-block finisher.
// R5: R4's verified 3-buffer counted-vmcnt pipeline (WAITVM -> s_barrier ->
// STAGE(buf[t+2]) -> TILE(buf[t]); never vmcnt(0) until the tail) with ONE
// geometry change: 4 waves (256 threads), wave grid 2x2, wave tile 128x64.
// Rationale: R0/R3/R4 all capped at MfmaUtil ~23-29% with NO pipe above
// ~40% of peak (MFMA ~20k cyc/SIMD, LDS-read ~34k cyc/CU @256B/cyc, over a
// 237k-cyc kernel) -- issue/dependency limited, not BW or drain limited
// (R4 removing the drain moved 102->99 only). Doubling the wave tile makes
// each scheduling quantum 32 MFMA on 12 ds_read_b128 (was 16 on 8):
// 2x FLOP per step-overhead, 1.33x less LDS traffic per FLOP, per-step
// MFMA time (~310 cyc/SIMD) now comparable to per-step LDS time
// (~375 cyc/CU). LDS stays 72 KB -> 2 blocks/CU (cross-block overlap
// keeps epilogue/prologue hidden). Acc = 32 v4f = 128 VGPR, ~210 total:
// fine at 2 waves/SIMD.
//
// Swizzle (verified 0-conflict in R4): slot chunk s of row r holds source
// chunk s ^ ((r>>1)&3); read slot = q ^ ((l15>>1)&3); DMA source permute
// csrc = (lane&3) ^ ((lane>>3)&3), rsub = lane>>2.
// MFMA accumulation stays global-k-ascending -> bit-identical numerics.
//
// Cross-block protocol unchanged: NO acquire/release fences (agent-scope
// ACQ_REL RMW emits buffer_inv/buffer_wbl2 = per-XCD L2 flush; measured
// +59% k-loop time). pos/partial use RELAXED agent-scope atomics;
// __syncthreads drains vmcnt(0) before the RELAXED counter RMW; RMW total
// order + control dependency orders the finisher's relaxed loads.
__global__ void __launch_bounds__(256)
gemm_fused(const unsigned short* __restrict__ xbf,
           const unsigned short* __restrict__ cbf,
           const int* __restrict__ labels,
           float* __restrict__ pos, float* __restrict__ partial,
           int* __restrict__ cnt,
           int Bt, int C, int D, int NT, float margin,
           float* __restrict__ out) {
    extern __shared__ short LDS[];   // 3 * TSH shorts = 72 KB

    const int t   = threadIdx.x;
    const int bid = blockIdx.x;
    const int xcd = bid & 7;
    const int per = bid >> 3;
    const int rowblk = (per >> 3) * 8 + xcd;
    const int nt     = per & 7;
    const int row0 = rowblk * BM;
    const int n0   = nt * BN;

    const int lane = t & 63;
    const int wave = t >> 6;          // 0..3
    const int wm = wave >> 1;         // 0..1 -> m offset wm*128
    const int wn = wave & 1;          // 0..1 -> n offset wn*64
    const int l15 = lane & 15, q = lane >> 4;

    // staging lane decomposition: 16 rows x 4 chunks per DMA instruction
    const int rsub = lane >> 2;                       // row within 16-row group
    const int csrc = (lane & 3) ^ ((lane >> 3) & 3);  // g(r) = (r>>1)&3

    // prefetch this thread's label (oldest vm op: retired by 1st WAITVM)
    int myLab = 0;
    if (t < BM) myLab = labels[row0 + t];

    v4f acc[8][4];
    #pragma unroll
    for (int i = 0; i < 8; ++i)
        #pragma unroll
        for (int j = 0; j < 4; ++j)
            acc[i][j] = (v4f){0.f, 0.f, 0.f, 0.f};

    // counted waits: "all but newest N VMEM ops retired"
    #define WAITVM6() do { asm volatile("s_waitcnt vmcnt(6)" ::: "memory"); } while (0)
    #define WAITVM0() do { asm volatile("s_waitcnt vmcnt(0)" ::: "memory"); } while (0)
    #define BARRIER() do { __builtin_amdgcn_s_barrier(); \
                           __builtin_amdgcn_sched_barrier(0); } while (0)

    // stage one 24 KB k-step tile (A 16 KB + B 8 KB): 6 DMA instrs/wave
    #define STAGE(buf_, k0_) do {                                            \
        _Pragma("unroll")                                                    \
        for (int p = 0; p < 4; ++p)                                          \
            load16_lds(&xbf[(size_t)(row0 + wave * 64 + p * 16 + rsub) * D   \
                            + (k0_) + csrc * 8],                             \
                       &LDS[(buf_) + (wave * 64 + p * 16) * BKH]);           \
        _Pragma("unroll")                                                    \
        for (int p = 0; p < 2; ++p)                                          \
            load16_lds(&cbf[(size_t)(n0 + wave * 32 + p * 16 + rsub) * D     \
                            + (k0_) + csrc * 8],                             \
                       &LDS[(buf_) + ASH + (wave * 32 + p * 16) * BKH]);     \
    } while (0)

    // one k-step: 12 ds_read_b128 + 32 MFMA; read slot = q ^ ((l15>>1)&3)
    #define TILE(buf_) do {                                                  \
        v8s a[8], b[4];                                                      \
        _Pragma("unroll")                                                    \
        for (int i = 0; i < 8; ++i)                                          \
            a[i] = *(const v8s*)&LDS[(buf_) + (wm * 128 + i * 16 + l15) * BKH \
                                     + ((q ^ ((l15 >> 1) & 3)) << 3)];       \
        _Pragma("unroll")                                                    \
        for (int j = 0; j < 4; ++j)                                          \
            b[j] = *(const v8s*)&LDS[(buf_) + ASH + (wn * 64 + j * 16 + l15) * BKH \
                                     + ((q ^ ((l15 >> 1) & 3)) << 3)];       \
        _Pragma("unroll")                                                    \
        for (int i = 0; i < 8; ++i)                                          \
            _Pragma("unroll")                                                \
            for (int j = 0; j < 4; ++j)                                      \
                acc[i][j] = __builtin_amdgcn_mfma_f32_16x16x32_bf16(         \
                    a[i], b[j], acc[i][j], 0, 0, 0);                         \
    } while (0)

    // rotating buffer base offsets (ints, not pointers: keeps AS3 inference)
    int bc = 0, b1 = TSH, b2 = 2 * TSH;

    // prologue: fill the pipeline 2 deep
    STAGE(bc, 0);
    STAGE(b1, BKH);

    const int KT = D / BKH;          // 16
    for (int kt = 0; kt + 2 < KT; ++kt) {
        WAITVM6();                   // buf[kt] landed; kt+1 stays in flight
        BARRIER();                   // all waves' buf[kt] visible; WAR safe
        STAGE(b2, (kt + 2) * BKH);   // refill depth (overwrites buf[kt-1])
        TILE(bc);
        const int tmp = bc; bc = b1; b1 = b2; b2 = tmp;
    }
    // kt = KT-2: no stage left to issue
    WAITVM6();
    BARRIER();
    TILE(bc);
    // kt = KT-1: final buffer -> full drain is exact here
    WAITVM0();
    BARRIER();
    TILE(b1);

    #undef STAGE
    #undef TILE
    #undef WAITVM6
    #undef WAITVM0
    #undef BARRIER

    __syncthreads();   // all reads done before LDS reuse; drains counters

    // ---- Epilogue (k-loop LDS dead; alias scratch) ----
    int*   Ls    = (int*)LDS;                     // [BM] labels (1 KB)
    float* sMinW = (float*)((char*)LDS + 1024);   // [2*BM] (2 KB)
    int*   sLast = (int*)((char*)LDS + 3072);
    float* wsum  = (float*)((char*)LDS + 3088);   // 4 floats
    if (t < BM) Ls[t] = myLab;
    __syncthreads();

    // dist = 1 - acc; stash pos at label col; row-min over valid cols.
    // C/D layout (16x16x32): col = lane&15, row = q*4 + reg
    #pragma unroll
    for (int i = 0; i < 8; ++i) {
        #pragma unroll
        for (int rg = 0; rg < 4; ++rg) {
            const int row_l = wm * 128 + i * 16 + q * 4 + rg;
            const int lab = Ls[row_l];
            float m = POS_INF;
            #pragma unroll
            for (int j = 0; j < 4; ++j) {
                const int col = n0 + wn * 64 + j * 16 + l15;
                const float d = 1.0f - acc[i][j][rg];
                if (col == lab)
                    __hip_atomic_store(&pos[row0 + row_l], d,
                                       __ATOMIC_RELAXED, __HIP_MEMORY_SCOPE_AGENT);
                else if (col < C) m = fminf(m, d);
            }
            m = fminf(m, __shfl_xor(m, 1, 64));
            m = fminf(m, __shfl_xor(m, 2, 64));
            m = fminf(m, __shfl_xor(m, 4, 64));
            m = fminf(m, __shfl_xor(m, 8, 64));
            if (l15 == 0) sMinW[wn * BM + row_l] = m;
        }
    }
    __syncthreads();
    if (t < BM) {
        const float m = fminf(sMinW[t], sMinW[BM + t]);
        __hip_atomic_store(&partial[(size_t)nt * Bt + row0 + t], m,
                           __ATOMIC_RELAXED, __HIP_MEMORY_SCOPE_AGENT);
    }
    __syncthreads();  // drains vmcnt(0): all stores at coherence point

    // Completion counter: RELAXED on purpose (no buffer_inv/buffer_wbl2).
    if (t == 0) {
        __builtin_amdgcn_s_waitcnt(0);  // belt-and-braces; already drained
        const int old = __hip_atomic_fetch_add(&cnt[rowblk], 1,
                                               __ATOMIC_RELAXED,
                                               __HIP_MEMORY_SCOPE_AGENT);
        *sLast = (old == NT - 1);
    }
    __syncthreads();
    if (!*sLast) return;

    float hng = 0.0f;
    if (t < BM) {
        const int r = row0 + t;
        float neg = POS_INF;
        for (int tt = 0; tt < NT; ++tt)
            neg = fminf(neg, __hip_atomic_load(&partial[(size_t)tt * Bt + r],
                                               __ATOMIC_RELAXED,
                                               __HIP_MEMORY_SCOPE_AGENT));
        const float p = __hip_atomic_load(&pos[r], __ATOMIC_RELAXED,
                                          __HIP_MEMORY_SCOPE_AGENT);
        hng = fmaxf(0.0f, p + margin - neg);
    }
    #pragma unroll
    for (int off = 32; off; off >>= 1) hng += __shfl_down(hng, off, 64);
    if (lane == 0) wsum[wave] = hng;
    __syncthreads();
    if (t == 0) {
        float s = 0.0f;
        #pragma unroll
        for (int w = 0; w < 4; ++w) s += wsum[w];
        atomicAdd(out, s * (1.0f / (float)Bt));
    }
}

extern "C" void kernel_launch(void* const* d_in, const int* in_sizes, int n_in,
                              void* d_out, int out_size, void* d_ws, size_t ws_size,
                              hipStream_t stream) {
    const float* x       = (const float*)d_in[0];
    const int*   labels  = (const int*)d_in[1];
    const float* centers = (const float*)d_in[2];
    float* out = (float*)d_out;

    const int Bt = in_sizes[1];           // 65536
    const int D  = in_sizes[0] / Bt;      // 512
    const int C  = in_sizes[2] / D;       // 1000
    const int NT = (C + BN - 1) / BN;     // 8
    const int CP = NT * BN;               // 1024
    const int NB = Bt / BM;               // 256 rowblocks

    char* ws = (char*)d_ws;
    unsigned short* cbf = (unsigned short*)ws;          // CP*D bf16 = 1 MB
    size_t off = (size_t)CP * D * 2;
    off = (off + 255) & ~(size_t)255;
    float* pos = (float*)(ws + off);      off += (size_t)Bt * 4;       // 256 KB
    float* partial = (float*)(ws + off);  off += (size_t)NT * Bt * 4;  // 2 MB
    int* cnt = (int*)(ws + off);          off += (size_t)NB * 4;
    off = (off + 255) & ~(size_t)255;
    unsigned short* xbf = (unsigned short*)(ws + off);   // 64 MB

    const size_t nx = (size_t)Bt * D;
    const int CB = CP / 4;                                // center blocks
    const int XB = (int)((nx / 8 + 255) / 256);           // convert blocks
    prep<<<CB + XB, 256, 0, stream>>>(centers, cbf, C, D, CP, CB, x, xbf, nx,
                                      cnt, NB, out);

    // 72 KB dynamic LDS needs the opt-in attribute (one-time, host-side,
    // not a stream op -> graph-capture safe).
    static bool lds_attr_set = false;
    if (!lds_attr_set) {
        hipFuncSetAttribute(reinterpret_cast<const void*>(gemm_fused),
                            hipFuncAttributeMaxDynamicSharedMemorySize,
                            3 * TSH * (int)sizeof(short));
        lds_attr_set = true;
    }
    gemm_fused<<<NB * NT, 256, 3 * TSH * sizeof(short), stream>>>(
        xbf, cbf, labels, pos, partial, cnt, Bt, C, D, NT, 1.0f, out);
}

// Round 6
// 292.296 us; speedup vs baseline: 1.1047x; 1.1047x over previous
//
#include <hip/hip_runtime.h>
#include <stdint.h>

typedef short v8s __attribute__((ext_vector_type(8)));
typedef short v4s __attribute__((ext_vector_type(4)));
typedef float v4f __attribute__((ext_vector_type(4)));

#define BM 256         // rows per block (8 waves, wave grid 4x2, 64x64/wave)
#define BN 128
#define BKH 32         // k-elements per step (A fp32: 128 B/row; B bf16: 64 B/row)
#define ABUF_SH (BM * 2 * BKH)        // A region in SHORT units (fp32 data): 16384 (32 KB)
#define BBUF_SH (BN * BKH)            // B region shorts: 4096 (8 KB)
#define TSH (ABUF_SH + BBUF_SH)       // shorts per buffer = 20480 (40 KB); x2 = 80 KB
#define POS_INF __builtin_inff()

typedef __attribute__((address_space(3))) unsigned int lds_uint;
typedef const __attribute__((address_space(1))) unsigned int glb_uint;

__device__ __forceinline__ void load16_lds(const void* g, void* l) {
    // 16B per lane, LDS dest = wave-uniform base + lane*16
    __builtin_amdgcn_global_load_lds((glb_uint*)g, (lds_uint*)l, 16, 0, 0);
}

__device__ __forceinline__ short f2bf(float f) {
    uint32_t u = __builtin_bit_cast(uint32_t, f);
    u += 0x7fffu + ((u >> 16) & 1u);
    return (short)(u >> 16);
}

// R6 prep: centers-only (x fp32->bf16 pass DELETED -- the GEMM now stages
// fp32 x directly via DMA and converts post-ds_read). Normalizes centers
// (1 row per wave), pads rows [C, CP) with zeros, zeroes rowblock counters
// and d_out. 256 blocks, ~3 us.
__global__ void prep(const float* __restrict__ centers,
                     unsigned short* __restrict__ cbf,
                     int C, int D, int CP, int CB,
                     int* __restrict__ cnt, int NB,
                     float* __restrict__ out) {
    const int b = blockIdx.x;
    const int t = threadIdx.x;
    if (b == 0 && t == 0) out[0] = 0.0f;
    const int g = b * 256 + t;
    if (g < NB) cnt[g] = 0;
    const int wave = t >> 6, lane = t & 63;
    const int row = b * 4 + wave;
    if (row >= CP) return;
    if (row >= C) {
        v4s z = {0, 0, 0, 0};
        for (int d = lane * 4; d < D; d += 256)
            *(v4s*)&cbf[(size_t)row * D + d] = z;
        return;
    }
    const float* src = centers + (size_t)row * D;
    float ss = 0.0f;
    for (int d = lane * 4; d < D; d += 256) {
        v4f f = *(const v4f*)&src[d];
        ss += f.x * f.x + f.y * f.y + f.z * f.z + f.w * f.w;
    }
    #pragma unroll
    for (int off = 32; off; off >>= 1) ss += __shfl_xor(ss, off, 64);
    const float rn = rsqrtf(ss);
    for (int d = lane * 4; d < D; d += 256) {
        v4f f = *(const v4f*)&src[d];
        v4s s;
        s.x = f2bf(f.x * rn); s.y = f2bf(f.y * rn);
        s.z = f2bf(f.z * rn); s.w = f2bf(f.w * rn);
        *(v4s*)&cbf[(size_t)row * D + d] = s;
    }
}

// Fused GEMM + row-min epilogue + last-block finisher.
// R6: R4's verified geometry and sync shape (256x128 tile, 8 waves 4x2,
// 64x64/wave, WAITVM -> s_barrier -> STAGE -> TILE, one barrier/step),
// but A is staged as RAW FP32 straight from x (global_load_lds is
// byte-agnostic DMA) and converted bf16 AFTER ds_read with 4x
// v_cvt_pk_bf16_f32 per fragment (RNE -- same rounding as prep's f2bf, so
// MFMA inputs and the final output are bit-identical to the xbf path).
// This deletes the 192 MB x-conversion prep pass (~30 us at HBM ceiling).
// Unlike R2 (per-lane global A loads: latency-exposed, 230 us) and the
// prior session's round 7 (manual staging: lost the DMA path), the DMA +
// LDS structure is unchanged -- only the staged bytes are fp32.
//
// LDS: A 32 KB + B 8 KB per step-buffer, 2 buffers = 80 KB -> 2 blocks/CU
// = 16 waves/CU (R4's proven-sufficient TLP). 2-buffer is legal with the
// R4 ordering: STAGE target buf was TILE'd one full step ago, and the
// step-top barrier orders those reads before the overwrite; each DMA gets
// ~a full TILE phase to land before its WAITVM.
//
// A-swizzle for 128 B rows (8 chunks of 16 B): slot s of row r holds
// source chunk s ^ ((r>>1)&7); DMA source chunk = (lane&7) ^ g where
// g = ((R0p>>1) + (lane>>4)) & 7 (R0p = instr's 8-row base); reader slot
// (2q+z) ^ (l15>>1), z in {0,1} -> 2 lanes per 16B slot per 16-lane
// phase (the proven-zero B pattern has 4/slot, so this is safer).
// B staging/read/swizzle: byte-identical to R4 (proven 0-conflict).
// MFMA accumulation stays global-k-ascending -> bit-identical numerics.
//
// Cross-block protocol unchanged: NO acquire/release fences (agent-scope
// ACQ_REL RMW emits buffer_inv/buffer_wbl2 = per-XCD L2 flush; measured
// +59% k-loop time). pos/partial use RELAXED agent-scope atomics;
// __syncthreads drains vmcnt(0) before the RELAXED counter RMW; RMW total
// order + control dependency orders the finisher's relaxed loads.
__global__ void __launch_bounds__(512)
gemm_fused(const float* __restrict__ x,
           const unsigned short* __restrict__ cbf,
           const int* __restrict__ labels,
           float* __restrict__ pos, float* __restrict__ partial,
           int* __restrict__ cnt,
           int Bt, int C, int D, int NT, float margin,
           float* __restrict__ out) {
    extern __shared__ short LDS[];   // 2 * TSH shorts = 80 KB

    const int t   = threadIdx.x;
    const int bid = blockIdx.x;
    const int xcd = bid & 7;
    const int per = bid >> 3;
    const int rowblk = (per >> 3) * 8 + xcd;
    const int nt     = per & 7;
    const int row0 = rowblk * BM;
    const int n0   = nt * BN;

    const int lane = t & 63;
    const int wave = t >> 6;          // 0..7
    const int wm = wave >> 1;         // 0..3 -> m offset wm*64
    const int wn = wave & 1;          // 0..1 -> n offset wn*64
    const int l15 = lane & 15, q = lane >> 4;

    // prefetch this thread's label (oldest vm op: retired by 1st WAITVM)
    int myLab = 0;
    if (t < BM) myLab = labels[row0 + t];

    v4f acc[4][4];
    #pragma unroll
    for (int i = 0; i < 4; ++i)
        #pragma unroll
        for (int j = 0; j < 4; ++j)
            acc[i][j] = (v4f){0.f, 0.f, 0.f, 0.f};

    #define WAITVM0() do { asm volatile("s_waitcnt vmcnt(0)" ::: "memory"); } while (0)
    #define BARRIER() do { __builtin_amdgcn_s_barrier(); \
                           __builtin_amdgcn_sched_barrier(0); } while (0)

    // stage one 40 KB k-step tile: A fp32 (4 DMA/wave, 8 rows x 8 chunks
    // each) + B bf16 (1 DMA/wave, 16 rows x 4 chunks) = 5 DMA instrs/wave
    #define STAGE(buf_, k0_) do {                                            \
        _Pragma("unroll")                                                    \
        for (int p = 0; p < 4; ++p) {                                        \
            const int gA_ = (lane & 7) ^ ((p * 4 + (lane >> 4)) & 7);        \
            load16_lds(&x[(size_t)(row0 + wave * 32 + p * 8 + (lane >> 3)) * D \
                          + (k0_) + gA_ * 4],                                \
                       &LDS[(buf_) + (wave * 32 + p * 8) * 64]);             \
        }                                                                    \
        load16_lds(&cbf[(size_t)(n0 + wave * 16 + (lane >> 2)) * D + (k0_)   \
                        + (((lane & 3) ^ ((lane >> 3) & 3)) * 8)],           \
                   &LDS[(buf_) + ABUF_SH + (wave * 16) * BKH]);              \
    } while (0)

    // one k-step: 8 fp32 ds_read_b128 + 16 cvt_pk + 4 bf16 ds_read + 16 MFMA
    #define TILE(buf_) do {                                                  \
        v8s a[4], b[4];                                                      \
        const float* Af_ = (const float*)&LDS[(buf_)];                       \
        _Pragma("unroll")                                                    \
        for (int j = 0; j < 4; ++j)                                          \
            b[j] = *(const v8s*)&LDS[(buf_) + ABUF_SH                        \
                                     + (wn * 64 + j * 16 + l15) * BKH        \
                                     + ((q ^ ((l15 >> 1) & 3)) << 3)];       \
        _Pragma("unroll")                                                    \
        for (int i = 0; i < 4; ++i) {                                        \
            const int m_ = wm * 64 + i * 16 + l15;                           \
            const int h_ = l15 >> 1;                                         \
            v4f f0 = *(const v4f*)&Af_[m_ * 32 + (((2 * q) ^ h_) << 2)];     \
            v4f f1 = *(const v4f*)&Af_[m_ * 32 + (((2 * q + 1) ^ h_) << 2)]; \
            union { v8s s; uint32_t u[4]; } au;                              \
            asm("v_cvt_pk_bf16_f32 %0, %1, %2"                               \
                : "=v"(au.u[0]) : "v"(f0.x), "v"(f0.y));                     \
            asm("v_cvt_pk_bf16_f32 %0, %1, %2"                               \
                : "=v"(au.u[1]) : "v"(f0.z), "v"(f0.w));                     \
            asm("v_cvt_pk_bf16_f32 %0, %1, %2"                               \
                : "=v"(au.u[2]) : "v"(f1.x), "v"(f1.y));                     \
            asm("v_cvt_pk_bf16_f32 %0, %1, %2"                               \
                : "=v"(au.u[3]) : "v"(f1.z), "v"(f1.w));                     \
            a[i] = au.s;                                                     \
        }                                                                    \
        _Pragma("unroll")                                                    \
        for (int i = 0; i < 4; ++i)                                          \
            _Pragma("unroll")                                                \
            for (int j = 0; j < 4; ++j)                                      \
                acc[i][j] = __builtin_amdgcn_mfma_f32_16x16x32_bf16(         \
                    a[i], b[j], acc[i][j], 0, 0, 0);                         \
    } while (0)

    int bc = 0, bnx = TSH;           // rotating buffer offsets (short units)

    STAGE(bc, 0);                    // prologue: tile 0 in flight

    const int KT = D / BKH;          // 16
    for (int kt = 0; kt < KT; ++kt) {
        WAITVM0();                   // my stage(kt) landed (issued a full
                                     // step ago; residual wait only)
        BARRIER();                   // everyone's stage(kt) landed; all
                                     // waves done reading buf[kt-1] -> WAR ok
        if (kt + 1 < KT) STAGE(bnx, (kt + 1) * BKH);
        TILE(bc);
        const int tmp = bc; bc = bnx; bnx = tmp;
    }

    #undef STAGE
    #undef TILE
    #undef WAITVM0
    #undef BARRIER

    __syncthreads();   // all reads done before LDS reuse; drains counters

    // ---- Epilogue (k-loop LDS dead; alias scratch) ----
    int*   Ls    = (int*)LDS;                     // [BM] labels (1 KB)
    float* sMinW = (float*)((char*)LDS + 1024);   // [2*BM] (2 KB)
    int*   sLast = (int*)((char*)LDS + 3072);
    float* wsum  = (float*)((char*)LDS + 3088);   // 8 floats
    if (t < BM) Ls[t] = myLab;
    __syncthreads();

    // dist = 1 - acc; stash pos at label col; row-min over valid cols.
    // C/D layout (16x16x32): col = lane&15, row = q*4 + reg
    #pragma unroll
    for (int i = 0; i < 4; ++i) {
        #pragma unroll
        for (int rg = 0; rg < 4; ++rg) {
            const int row_l = wm * 64 + i * 16 + q * 4 + rg;
            const int lab = Ls[row_l];
            float m = POS_INF;
            #pragma unroll
            for (int j = 0; j < 4; ++j) {
                const int col = n0 + wn * 64 + j * 16 + l15;
                const float d = 1.0f - acc[i][j][rg];
                if (col == lab)
                    __hip_atomic_store(&pos[row0 + row_l], d,
                                       __ATOMIC_RELAXED, __HIP_MEMORY_SCOPE_AGENT);
                else if (col < C) m = fminf(m, d);
            }
            m = fminf(m, __shfl_xor(m, 1, 64));
            m = fminf(m, __shfl_xor(m, 2, 64));
            m = fminf(m, __shfl_xor(m, 4, 64));
            m = fminf(m, __shfl_xor(m, 8, 64));
            if (l15 == 0) sMinW[wn * BM + row_l] = m;
        }
    }
    __syncthreads();
    if (t < BM) {
        const float m = fminf(sMinW[t], sMinW[BM + t]);
        __hip_atomic_store(&partial[(size_t)nt * Bt + row0 + t], m,
                           __ATOMIC_RELAXED, __HIP_MEMORY_SCOPE_AGENT);
    }
    __syncthreads();  // drains vmcnt(0): all stores at coherence point

    // Completion counter: RELAXED on purpose (no buffer_inv/buffer_wbl2).
    if (t == 0) {
        __builtin_amdgcn_s_waitcnt(0);  // belt-and-braces; already drained
        const int old = __hip_atomic_fetch_add(&cnt[rowblk], 1,
                                               __ATOMIC_RELAXED,
                                               __HIP_MEMORY_SCOPE_AGENT);
        *sLast = (old == NT - 1);
    }
    __syncthreads();
    if (!*sLast) return;

    float hng = 0.0f;
    if (t < BM) {
        const int r = row0 + t;
        float neg = POS_INF;
        for (int tt = 0; tt < NT; ++tt)
            neg = fminf(neg, __hip_atomic_load(&partial[(size_t)tt * Bt + r],
                                               __ATOMIC_RELAXED,
                                               __HIP_MEMORY_SCOPE_AGENT));
        const float p = __hip_atomic_load(&pos[r], __ATOMIC_RELAXED,
                                          __HIP_MEMORY_SCOPE_AGENT);
        hng = fmaxf(0.0f, p + margin - neg);
    }
    #pragma unroll
    for (int off = 32; off; off >>= 1) hng += __shfl_down(hng, off, 64);
    if (lane == 0) wsum[wave] = hng;
    __syncthreads();
    if (t == 0) {
        float s = 0.0f;
        #pragma unroll
        for (int w = 0; w < 8; ++w) s += wsum[w];
        atomicAdd(out, s * (1.0f / (float)Bt));
    }
}

extern "C" void kernel_launch(void* const* d_in, const int* in_sizes, int n_in,
                              void* d_out, int out_size, void* d_ws, size_t ws_size,
                              hipStream_t stream) {
    const float* x       = (const float*)d_in[0];
    const int*   labels  = (const int*)d_in[1];
    const float* centers = (const float*)d_in[2];
    float* out = (float*)d_out;

    const int Bt = in_sizes[1];           // 65536
    const int D  = in_sizes[0] / Bt;      // 512
    const int C  = in_sizes[2] / D;       // 1000
    const int NT = (C + BN - 1) / BN;     // 8
    const int CP = NT * BN;               // 1024
    const int NB = Bt / BM;               // 256 rowblocks

    char* ws = (char*)d_ws;
    unsigned short* cbf = (unsigned short*)ws;          // CP*D bf16 = 1 MB
    size_t off = (size_t)CP * D * 2;
    off = (off + 255) & ~(size_t)255;
    float* pos = (float*)(ws + off);      off += (size_t)Bt * 4;       // 256 KB
    float* partial = (float*)(ws + off);  off += (size_t)NT * Bt * 4;  // 2 MB
    int* cnt = (int*)(ws + off);          off += (size_t)NB * 4;

    const int CB = CP / 4;                                // 256 center blocks
    prep<<<CB, 256, 0, stream>>>(centers, cbf, C, D, CP, CB, cnt, NB, out);

    // 80 KB dynamic LDS needs the opt-in attribute (one-time, host-side,
    // not a stream op -> graph-capture safe).
    static bool lds_attr_set = false;
    if (!lds_attr_set) {
        hipFuncSetAttribute(reinterpret_cast<const void*>(gemm_fused),
                            hipFuncAttributeMaxDynamicSharedMemorySize,
                            2 * TSH * (int)sizeof(short));
        lds_attr_set = true;
    }
    gemm_fused<<<NB * NT, 512, 2 * TSH * sizeof(short), stream>>>(
        x, cbf, labels, pos, partial, cnt, Bt, C, D, NT, 1.0f, out);
}